// Round 7
// baseline (463.238 us; speedup 1.0000x reference)
//
#include <hip/hip_runtime.h>
#include <stdint.h>

// VectorQuantizer — f32 I/O confirmed. d_in[0]=z [16384,64], d_in[1]=e [8192,64];
// d_out f32: [z_q 16384*64][idx-as-float 16384]. d_ws >= 16MB confirmed (round 5).
//
// FROZEN exact numerics (rescore path only):
//   sz,se: scalar pairwise-8; c: 4 lanes (k mod 4), mul/add separately rounded,
//   16-chunks ascending, reversed sub-blocks (+12,+8,+4,+0), hadd (q0+q1)+(q2+q3);
//   A=fl(sz+se); d=fl(A-2c); argmin strict-<, first (smallest) index wins.
//
// Round-7: keep bf16 MFMA prefilter (chunk-max of c, BAND capture bound 9.4e-5 <
// 1.25e-4). Rescore restructured: select -> compact worklist -> flat wave-per-item
// exact eval -> 64-bit atomicMin(packed (d_bits<<32)|j) [d>0 so bits monotone;
// min is order-invariant -> deterministic]. zq reads packed directly.

#define NROWS 16384
#define NE    8192
#define D     64
#define BN    128
#define NCH   (NE / BN)     // 64
#define BAND  1.25e-4f

typedef __attribute__((ext_vector_type(8))) short short8;
typedef __attribute__((ext_vector_type(4))) float f32x4;

// ---------- frozen exact helpers ----------
__device__ __forceinline__ float sumsq_pairwise8(const float* x) {
    float r8[8];
    #pragma unroll
    for (int l = 0; l < 8; ++l) r8[l] = __fmul_rn(x[l], x[l]);
    #pragma unroll
    for (int i = 8; i < 64; i += 8)
        #pragma unroll
        for (int l = 0; l < 8; ++l)
            r8[l] = __fadd_rn(r8[l], __fmul_rn(x[i + l], x[i + l]));
    return __fadd_rn(__fadd_rn(__fadd_rn(r8[0], r8[1]), __fadd_rn(r8[2], r8[3])),
                     __fadd_rn(__fadd_rn(r8[4], r8[5]), __fadd_rn(r8[6], r8[7])));
}

__device__ __forceinline__ float dot_numpy(const float* zr, const float* ef) {
    float q0 = 0.f, q1 = 0.f, q2 = 0.f, q3 = 0.f;
    #pragma unroll
    for (int cc = 0; cc < 4; ++cc) {
        const int b = cc * 16;
        q0 = __fadd_rn(q0, __fmul_rn(zr[b + 12], ef[b + 12]));
        q1 = __fadd_rn(q1, __fmul_rn(zr[b + 13], ef[b + 13]));
        q2 = __fadd_rn(q2, __fmul_rn(zr[b + 14], ef[b + 14]));
        q3 = __fadd_rn(q3, __fmul_rn(zr[b + 15], ef[b + 15]));
        q0 = __fadd_rn(q0, __fmul_rn(zr[b +  8], ef[b +  8]));
        q1 = __fadd_rn(q1, __fmul_rn(zr[b +  9], ef[b +  9]));
        q2 = __fadd_rn(q2, __fmul_rn(zr[b + 10], ef[b + 10]));
        q3 = __fadd_rn(q3, __fmul_rn(zr[b + 11], ef[b + 11]));
        q0 = __fadd_rn(q0, __fmul_rn(zr[b +  4], ef[b +  4]));
        q1 = __fadd_rn(q1, __fmul_rn(zr[b +  5], ef[b +  5]));
        q2 = __fadd_rn(q2, __fmul_rn(zr[b +  6], ef[b +  6]));
        q3 = __fadd_rn(q3, __fmul_rn(zr[b +  7], ef[b +  7]));
        q0 = __fadd_rn(q0, __fmul_rn(zr[b +  0], ef[b +  0]));
        q1 = __fadd_rn(q1, __fmul_rn(zr[b +  1], ef[b +  1]));
        q2 = __fadd_rn(q2, __fmul_rn(zr[b +  2], ef[b +  2]));
        q3 = __fadd_rn(q3, __fmul_rn(zr[b +  3], ef[b +  3]));
    }
    return __fadd_rn(__fadd_rn(q0, q1), __fadd_rn(q2, q3));
}

__device__ __forceinline__ uint32_t bf16rn(float f) {
    union { float f; uint32_t u; } c; c.f = f;
    return (c.u + 0x7FFFu + ((c.u >> 16) & 1u)) >> 16;
}
__device__ __forceinline__ uint32_t pk2(float lo, float hi) {
    return bf16rn(lo) | (bf16rn(hi) << 16);
}

// ---------- phase 0: f32 -> bf16 (RN) ----------
__global__ __launch_bounds__(256)
void vq_convert(const float* __restrict__ z, const float* __restrict__ e,
                uint32_t* __restrict__ zb, uint32_t* __restrict__ eb)
{
    const int i = blockIdx.x * 256 + threadIdx.x;
    const int nz = NROWS * D / 8;
    const int ne = NE * D / 8;
    if (i < nz) {
        const float4 a = ((const float4*)z)[i * 2];
        const float4 b = ((const float4*)z)[i * 2 + 1];
        uint4 o; o.x = pk2(a.x, a.y); o.y = pk2(a.z, a.w);
        o.z = pk2(b.x, b.y); o.w = pk2(b.z, b.w);
        ((uint4*)zb)[i] = o;
    } else if (i < nz + ne) {
        const int k = i - nz;
        const float4 a = ((const float4*)e)[k * 2];
        const float4 b = ((const float4*)e)[k * 2 + 1];
        uint4 o; o.x = pk2(a.x, a.y); o.y = pk2(a.z, a.w);
        o.z = pk2(b.x, b.y); o.w = pk2(b.z, b.w);
        ((uint4*)eb)[k] = o;
    }
}

// ---------- phase 0b: exact sz/se, init packed + counter ----------
__global__ __launch_bounds__(256)
void vq_prep(const float* __restrict__ z, const float* __restrict__ e,
             float* __restrict__ sz_arr, float* __restrict__ se_arr,
             unsigned long long* __restrict__ packed,
             unsigned int* __restrict__ counter)
{
    const int i = blockIdx.x * 256 + threadIdx.x;
    if (i == 0) *counter = 0u;
    if (i < NROWS) {
        const float* p = z + (size_t)i * D;
        float x[D];
        #pragma unroll
        for (int k = 0; k < D; k += 4) {
            const float4 v = *(const float4*)(p + k);
            x[k] = v.x; x[k + 1] = v.y; x[k + 2] = v.z; x[k + 3] = v.w;
        }
        sz_arr[i] = sumsq_pairwise8(x);
        packed[i] = 0xFFFFFFFFFFFFFFFFull;
    } else if (i < NROWS + NE) {
        const int j = i - NROWS;
        const float* p = e + (size_t)j * D;
        float x[D];
        #pragma unroll
        for (int k = 0; k < D; k += 4) {
            const float4 v = *(const float4*)(p + k);
            x[k] = v.x; x[k + 1] = v.y; x[k + 2] = v.z; x[k + 3] = v.w;
        }
        se_arr[j] = sumsq_pairwise8(x);
    }
}

// ---------- phase 1: MFMA GEMM + per-(row,chunk) max (unchanged, verified) ----------
__global__ __launch_bounds__(256)
void vq_scan_mfma(const uint16_t* __restrict__ zb, const uint16_t* __restrict__ eb,
                  float* __restrict__ cmax)
{
    __shared__ uint16_t elds[BN][72];
    __shared__ float    rmld[4][64][20];

    const int tid  = threadIdx.x;
    const int lane = tid & 63, w = tid >> 6;
    const int mb   = blockIdx.x >> 5;
    const int jb   = blockIdx.x & 31;
    const int row0 = mb * 256 + w * 64;
    const int l15  = lane & 15, l4 = lane >> 4;

    short8 af[4][2];
    #pragma unroll
    for (int m = 0; m < 4; ++m)
        #pragma unroll
        for (int h = 0; h < 2; ++h)
            af[m][h] = *(const short8*)(zb + (size_t)(row0 + m * 16 + l15) * D + h * 32 + l4 * 8);

    const f32x4 z4 = {0.f, 0.f, 0.f, 0.f};

    #pragma unroll 1
    for (int c = 0; c < 2; ++c) {
        const int j0 = jb * 256 + c * BN;
        {
            const int srow = tid >> 1, shalf = tid & 1;
            const uint16_t* sp = eb + (size_t)(j0 + srow) * D + shalf * 32;
            uint16_t* dp = &elds[srow][shalf * 32];
            #pragma unroll
            for (int q = 0; q < 4; ++q)
                *(short8*)(dp + q * 8) = *(const short8*)(sp + q * 8);
        }
        __syncthreads();

        f32x4 rm[4];
        #pragma unroll
        for (int m = 0; m < 4; ++m) rm[m] = {-3.0e38f, -3.0e38f, -3.0e38f, -3.0e38f};

        #pragma unroll 1
        for (int n = 0; n < 8; ++n) {
            const uint16_t* bp = &elds[n * 16 + l15][l4 * 8];
            const short8 b0 = *(const short8*)(bp);
            const short8 b1 = *(const short8*)(bp + 32);
            #pragma unroll
            for (int m = 0; m < 4; ++m) {
                f32x4 acc = __builtin_amdgcn_mfma_f32_16x16x32_bf16(af[m][0], b0, z4, 0, 0, 0);
                acc = __builtin_amdgcn_mfma_f32_16x16x32_bf16(af[m][1], b1, acc, 0, 0, 0);
                #pragma unroll
                for (int r = 0; r < 4; ++r) rm[m][r] = fmaxf(rm[m][r], acc[r]);
            }
        }

        #pragma unroll
        for (int m = 0; m < 4; ++m)
            *(f32x4*)&rmld[w][lane][m * 4] = rm[m];
        const int r  = lane;
        const int mm = r >> 4, rg = r & 3, lg = ((r & 15) >> 2) * 16;
        float v = rmld[w][lg][mm * 4 + rg];
        #pragma unroll
        for (int i = 1; i < 16; ++i) v = fmaxf(v, rmld[w][lg + i][mm * 4 + rg]);
        cmax[(size_t)(row0 + r) * NCH + (jb * 2 + c)] = v;
        __syncthreads();
    }
}

// ---------- phase 2a: select in-band chunks -> compact worklist ----------
__global__ __launch_bounds__(256)
void vq_select(const float* __restrict__ cmax, uint32_t* __restrict__ worklist,
               unsigned int* __restrict__ counter)
{
    const int lane = threadIdx.x & 63, w = threadIdx.x >> 6;
    const int row = blockIdx.x * 4 + w;

    const float ci = cmax[(size_t)row * NCH + lane];
    float cm = ci;
    #pragma unroll
    for (int o = 1; o < 64; o <<= 1) cm = fmaxf(cm, __shfl_xor(cm, o, 64));
    const bool hit = ci >= cm - BAND;
    const unsigned long long sel = __ballot(hit);

    unsigned int base = 0;
    if (lane == 0) base = atomicAdd(counter, (unsigned int)__popcll(sel));
    base = (unsigned int)__shfl((int)base, 0, 64);
    if (hit) {
        const unsigned int rank = (unsigned int)__popcll(sel & ((1ull << lane) - 1ull));
        worklist[base + rank] = ((unsigned int)row << 6) | (unsigned int)lane;
    }
}

// ---------- phase 2b: flat exact eval, one atomicMin per item ----------
__global__ __launch_bounds__(256)
void vq_eval(const float* __restrict__ z, const float* __restrict__ e,
             const float* __restrict__ sz_arr, const float* __restrict__ se_arr,
             const uint32_t* __restrict__ worklist,
             const unsigned int* __restrict__ counter,
             unsigned long long* __restrict__ packed)
{
    const int lane = threadIdx.x & 63;
    const int gw   = (blockIdx.x * 256 + threadIdx.x) >> 6;
    const int nw   = gridDim.x * 4;
    const unsigned int cnt = *counter;

    for (unsigned int it = gw; it < cnt; it += nw) {
        const uint32_t item = worklist[it];
        const int row = (int)(item >> 6), ch = (int)(item & 63u);

        const float* zp = z + (size_t)row * D;
        float zr[D];
        #pragma unroll
        for (int k = 0; k < D; k += 4) {
            const float4 v = *(const float4*)(zp + k);
            zr[k] = v.x; zr[k + 1] = v.y; zr[k + 2] = v.z; zr[k + 3] = v.w;
        }
        const float sz = sz_arr[row];

        float bd = 3.0e38f; int bj = 0x7FFFFFFF;
        #pragma unroll
        for (int s = 0; s < 2; ++s) {
            const int j = ch * BN + lane * 2 + s;
            const float* ep = e + (size_t)j * D;
            float ef[D];
            #pragma unroll
            for (int k = 0; k < D; k += 4) {
                const float4 v = *(const float4*)(ep + k);
                ef[k] = v.x; ef[k + 1] = v.y; ef[k + 2] = v.z; ef[k + 3] = v.w;
            }
            const float A  = __fadd_rn(sz, se_arr[j]);          // fl(sz + se)
            const float cc = dot_numpy(zr, ef);                 // exact numpy order
            const float dd = __fsub_rn(A, __fadd_rn(cc, cc));   // fl(A - 2c)
            if (dd < bd) { bd = dd; bj = j; }                   // ascending s: first wins
        }
        float d = bd; int j = bj;
        #pragma unroll
        for (int o = 1; o < 64; o <<= 1) {
            const float od = __shfl_xor(d, o, 64);
            const int   oj = __shfl_xor(j, o, 64);
            if (od < d || (od == d && oj < j)) { d = od; j = oj; }
        }
        if (lane == 0) {
            // d > 0 always (min row-norm^2 >> 0) -> float bits monotone
            const unsigned long long key =
                ((unsigned long long)__float_as_uint(d) << 32) | (unsigned int)j;
            atomicMin(packed + row, key);
        }
    }
}

// ---------- phase 3: z_q + idx from packed ----------
__global__ __launch_bounds__(256)
void vq_zq(const float* __restrict__ z, const float* __restrict__ e,
           const unsigned long long* __restrict__ packed, float* __restrict__ out)
{
    const size_t m = (size_t)blockIdx.x * 256 + threadIdx.x;
    const int r = (int)(m >> 6), k = (int)(m & 63);
    const int sel = (int)(packed[r] & 0xFFFFFFFFull);
    const float zv = z[m];
    const float ev = e[(size_t)sel * D + k];
    out[m] = __fadd_rn(zv, __fsub_rn(ev, zv));
    if (k == 0) out[(size_t)NROWS * D + r] = (float)sel;
}

extern "C" void kernel_launch(void* const* d_in, const int* in_sizes, int n_in,
                              void* d_out, int out_size, void* d_ws, size_t ws_size,
                              hipStream_t stream)
{
    const float* z = (const float*)d_in[0];
    const float* e = (const float*)d_in[1];
    float* out = (float*)d_out;

    char* ws = (char*)d_ws;
    const size_t MB = 1024 * 1024, KB = 1024;
    uint16_t* zb                 = (uint16_t*)(ws);                    // 2 MB
    uint16_t* eb                 = (uint16_t*)(ws + 2 * MB);           // 1 MB
    float* cmaxb                 = (float*)(ws + 3 * MB);              // 4 MB
    float* sz_arr                = (float*)(ws + 7 * MB);              // 64 KB
    float* se_arr                = (float*)(ws + 7 * MB + 64 * KB);    // 32 KB
    unsigned long long* packed   = (unsigned long long*)(ws + 7 * MB + 96 * KB);  // 128 KB
    unsigned int* counter        = (unsigned int*)(ws + 7 * MB + 224 * KB);       // 16 B
    uint32_t* worklist           = (uint32_t*)(ws + 7 * MB + 256 * KB);           // 4 MB

    vq_convert  <<<dim3(768),                 dim3(256), 0, stream>>>(z, e, (uint32_t*)zb, (uint32_t*)eb);
    vq_prep     <<<dim3((NROWS + NE) / 256),  dim3(256), 0, stream>>>(z, e, sz_arr, se_arr, packed, counter);
    vq_scan_mfma<<<dim3(2048),                dim3(256), 0, stream>>>(zb, eb, cmaxb);
    vq_select   <<<dim3(NROWS / 4),           dim3(256), 0, stream>>>(cmaxb, worklist, counter);
    vq_eval     <<<dim3(1024),                dim3(256), 0, stream>>>(z, e, sz_arr, se_arr, worklist, counter, packed);
    vq_zq       <<<dim3(NROWS * D / 256),     dim3(256), 0, stream>>>(z, e, packed, out);
}

// Round 8
// 260.924 us; speedup vs baseline: 1.7754x; 1.7754x over previous
//
#include <hip/hip_runtime.h>
#include <stdint.h>

// VectorQuantizer — f32 I/O confirmed. d_in[0]=z [16384,64], d_in[1]=e [8192,64];
// d_out f32: [z_q 16384*64][idx-as-float 16384]. d_ws >= 16MB confirmed.
//
// FROZEN exact numerics (rescore path only):
//   sz,se: scalar pairwise-8; c: 4 lanes (k mod 4), mul/add separately rounded,
//   16-chunks ascending, reversed sub-blocks (+12,+8,+4,+0), hadd (q0+q1)+(q2+q3);
//   A=fl(sz+se); d=fl(A-2c); argmin strict-<, first (smallest) index wins.
//
// Round-8: revert to round-6 pipeline (no atomics/worklist — that cost +190us).
// Rescore rewritten as STREAMING: z-row in LDS (broadcast b128 reads), e-rows
// streamed float4-granule-major in the frozen accumulation order; only 8 q-accums
// live per lane -> ~50 true VGPRs, no rematerialized whole-row arrays (the
// round-6/7 disease: 136-reg arrays clamped to 56 -> serial L2 re-reads).

#define NROWS 16384
#define NE    8192
#define D     64
#define BN    128
#define NCH   (NE / BN)     // 64
#define BAND  1.25e-4f

typedef __attribute__((ext_vector_type(8))) short short8;
typedef __attribute__((ext_vector_type(4))) float f32x4;

// ---------- frozen exact helpers ----------
__device__ __forceinline__ float sumsq_pairwise8(const float* x) {
    float r8[8];
    #pragma unroll
    for (int l = 0; l < 8; ++l) r8[l] = __fmul_rn(x[l], x[l]);
    #pragma unroll
    for (int i = 8; i < 64; i += 8)
        #pragma unroll
        for (int l = 0; l < 8; ++l)
            r8[l] = __fadd_rn(r8[l], __fmul_rn(x[i + l], x[i + l]));
    return __fadd_rn(__fadd_rn(__fadd_rn(r8[0], r8[1]), __fadd_rn(r8[2], r8[3])),
                     __fadd_rn(__fadd_rn(r8[4], r8[5]), __fadd_rn(r8[6], r8[7])));
}

__device__ __forceinline__ uint32_t bf16rn(float f) {
    union { float f; uint32_t u; } c; c.f = f;
    return (c.u + 0x7FFFu + ((c.u >> 16) & 1u)) >> 16;
}
__device__ __forceinline__ uint32_t pk2(float lo, float hi) {
    return bf16rn(lo) | (bf16rn(hi) << 16);
}

// ---------- phase 0a: f32 -> bf16 (RN) ----------
__global__ __launch_bounds__(256)
void vq_convert(const float* __restrict__ z, const float* __restrict__ e,
                uint32_t* __restrict__ zb, uint32_t* __restrict__ eb)
{
    const int i = blockIdx.x * 256 + threadIdx.x;
    const int nz = NROWS * D / 8;
    const int ne = NE * D / 8;
    if (i < nz) {
        const float4 a = ((const float4*)z)[i * 2];
        const float4 b = ((const float4*)z)[i * 2 + 1];
        uint4 o; o.x = pk2(a.x, a.y); o.y = pk2(a.z, a.w);
        o.z = pk2(b.x, b.y); o.w = pk2(b.z, b.w);
        ((uint4*)zb)[i] = o;
    } else if (i < nz + ne) {
        const int k = i - nz;
        const float4 a = ((const float4*)e)[k * 2];
        const float4 b = ((const float4*)e)[k * 2 + 1];
        uint4 o; o.x = pk2(a.x, a.y); o.y = pk2(a.z, a.w);
        o.z = pk2(b.x, b.y); o.w = pk2(b.z, b.w);
        ((uint4*)eb)[k] = o;
    }
}

// ---------- phase 0b: exact sz[row], se[j] (no atomics) ----------
__global__ __launch_bounds__(256)
void vq_prep(const float* __restrict__ z, const float* __restrict__ e,
             float* __restrict__ sz_arr, float* __restrict__ se_arr)
{
    const int i = blockIdx.x * 256 + threadIdx.x;
    const float* p;
    float* dst;
    if (i < NROWS) { p = z + (size_t)i * D; dst = sz_arr + i; }
    else if (i < NROWS + NE) { p = e + (size_t)(i - NROWS) * D; dst = se_arr + (i - NROWS); }
    else return;
    float x[D];
    #pragma unroll
    for (int k = 0; k < D; k += 4) {
        const float4 v = *(const float4*)(p + k);
        x[k] = v.x; x[k + 1] = v.y; x[k + 2] = v.z; x[k + 3] = v.w;
    }
    *dst = sumsq_pairwise8(x);
}

// ---------- phase 1: MFMA GEMM + per-(row,chunk) max (verified, unchanged) ----------
__global__ __launch_bounds__(256)
void vq_scan_mfma(const uint16_t* __restrict__ zb, const uint16_t* __restrict__ eb,
                  float* __restrict__ cmax)
{
    __shared__ uint16_t elds[BN][72];
    __shared__ float    rmld[4][64][20];

    const int tid  = threadIdx.x;
    const int lane = tid & 63, w = tid >> 6;
    const int mb   = blockIdx.x >> 5;
    const int jb   = blockIdx.x & 31;
    const int row0 = mb * 256 + w * 64;
    const int l15  = lane & 15, l4 = lane >> 4;

    short8 af[4][2];
    #pragma unroll
    for (int m = 0; m < 4; ++m)
        #pragma unroll
        for (int h = 0; h < 2; ++h)
            af[m][h] = *(const short8*)(zb + (size_t)(row0 + m * 16 + l15) * D + h * 32 + l4 * 8);

    const f32x4 z4 = {0.f, 0.f, 0.f, 0.f};

    #pragma unroll 1
    for (int c = 0; c < 2; ++c) {
        const int j0 = jb * 256 + c * BN;
        {
            const int srow = tid >> 1, shalf = tid & 1;
            const uint16_t* sp = eb + (size_t)(j0 + srow) * D + shalf * 32;
            uint16_t* dp = &elds[srow][shalf * 32];
            #pragma unroll
            for (int q = 0; q < 4; ++q)
                *(short8*)(dp + q * 8) = *(const short8*)(sp + q * 8);
        }
        __syncthreads();

        f32x4 rm[4];
        #pragma unroll
        for (int m = 0; m < 4; ++m) rm[m] = {-3.0e38f, -3.0e38f, -3.0e38f, -3.0e38f};

        #pragma unroll 1
        for (int n = 0; n < 8; ++n) {
            const uint16_t* bp = &elds[n * 16 + l15][l4 * 8];
            const short8 b0 = *(const short8*)(bp);
            const short8 b1 = *(const short8*)(bp + 32);
            #pragma unroll
            for (int m = 0; m < 4; ++m) {
                f32x4 acc = __builtin_amdgcn_mfma_f32_16x16x32_bf16(af[m][0], b0, z4, 0, 0, 0);
                acc = __builtin_amdgcn_mfma_f32_16x16x32_bf16(af[m][1], b1, acc, 0, 0, 0);
                #pragma unroll
                for (int r = 0; r < 4; ++r) rm[m][r] = fmaxf(rm[m][r], acc[r]);
            }
        }

        #pragma unroll
        for (int m = 0; m < 4; ++m)
            *(f32x4*)&rmld[w][lane][m * 4] = rm[m];
        const int r  = lane;
        const int mm = r >> 4, rg = r & 3, lg = ((r & 15) >> 2) * 16;
        float v = rmld[w][lg][mm * 4 + rg];
        #pragma unroll
        for (int i = 1; i < 16; ++i) v = fmaxf(v, rmld[w][lg + i][mm * 4 + rg]);
        cmax[(size_t)(row0 + r) * NCH + (jb * 2 + c)] = v;
        __syncthreads();
    }
}

// ---------- phase 2: streaming exact rescore, wave per row ----------
__global__ __launch_bounds__(256)
void vq_rescore(const float* __restrict__ z, const float* __restrict__ e,
                const float* __restrict__ sz_arr, const float* __restrict__ se_arr,
                const float* __restrict__ cmax, float* __restrict__ out)
{
    __shared__ float zl[4][D];

    const int lane = threadIdx.x & 63, w = threadIdx.x >> 6;
    const int row = blockIdx.x * 4 + w;

    // band-select chunks
    const float ci = cmax[(size_t)row * NCH + lane];
    float cm = ci;
    #pragma unroll
    for (int o = 1; o < 64; o <<= 1) cm = fmaxf(cm, __shfl_xor(cm, o, 64));
    unsigned long long sel = __ballot(ci >= cm - BAND);

    // stage z row into LDS (one float per lane); same-wave DS in-order
    zl[w][lane] = z[(size_t)row * D + lane];

    const float sz = sz_arr[row];

    float bd = 3.0e38f; int bj = 0x7FFFFFFF;
    while (sel) {
        const int ch = __builtin_ctzll(sel); sel &= sel - 1;   // ascending chunks
        const int j0 = ch * BN + lane * 2;
        const float* ep0 = e + (size_t)j0 * D;
        const float* ep1 = ep0 + D;

        // frozen dot order: per 16-chunk cc (ascending), granules +12,+8,+4,+0;
        // q_l accumulates k===l (mod 4); mul and add separately rounded.
        float q00 = 0.f, q01 = 0.f, q02 = 0.f, q03 = 0.f;   // j0
        float q10 = 0.f, q11 = 0.f, q12 = 0.f, q13 = 0.f;   // j1
        #pragma unroll
        for (int cc = 0; cc < 4; ++cc) {
            #pragma unroll
            for (int sb = 3; sb >= 0; --sb) {
                const int b = cc * 16 + sb * 4;
                const float4 zv = *(const float4*)&zl[w][b];       // LDS broadcast
                const float4 e0 = *(const float4*)(ep0 + b);
                const float4 e1 = *(const float4*)(ep1 + b);
                q00 = __fadd_rn(q00, __fmul_rn(zv.x, e0.x));
                q01 = __fadd_rn(q01, __fmul_rn(zv.y, e0.y));
                q02 = __fadd_rn(q02, __fmul_rn(zv.z, e0.z));
                q03 = __fadd_rn(q03, __fmul_rn(zv.w, e0.w));
                q10 = __fadd_rn(q10, __fmul_rn(zv.x, e1.x));
                q11 = __fadd_rn(q11, __fmul_rn(zv.y, e1.y));
                q12 = __fadd_rn(q12, __fmul_rn(zv.z, e1.z));
                q13 = __fadd_rn(q13, __fmul_rn(zv.w, e1.w));
            }
        }
        const float c0 = __fadd_rn(__fadd_rn(q00, q01), __fadd_rn(q02, q03));
        const float c1 = __fadd_rn(__fadd_rn(q10, q11), __fadd_rn(q12, q13));
        const float A0 = __fadd_rn(sz, se_arr[j0]);
        const float A1 = __fadd_rn(sz, se_arr[j0 + 1]);
        const float d0 = __fsub_rn(A0, __fadd_rn(c0, c0));
        const float d1 = __fsub_rn(A1, __fadd_rn(c1, c1));

        float d = d0; int j = j0;
        if (d1 < d) { d = d1; j = j0 + 1; }                 // tie keeps smaller j
        #pragma unroll
        for (int o = 1; o < 64; o <<= 1) {
            const float od = __shfl_xor(d, o, 64);
            const int   oj = __shfl_xor(j, o, 64);
            if (od < d || (od == d && oj < j)) { d = od; j = oj; }
        }
        if (d < bd || (d == bd && j < bj)) { bd = d; bj = j; }
    }
    if (lane == 0) out[(size_t)NROWS * D + row] = (float)bj;
}

// ---------- phase 3: z_q = fl(z + fl(e[idx] - z)) ----------
__global__ __launch_bounds__(256)
void vq_zq(const float* __restrict__ z, const float* __restrict__ e,
           float* __restrict__ out)
{
    const size_t m = (size_t)blockIdx.x * 256 + threadIdx.x;
    const int r = (int)(m >> 6), k = (int)(m & 63);
    const int sel = (int)out[(size_t)NROWS * D + r];
    const float zv = z[m];
    const float ev = e[(size_t)sel * D + k];
    out[m] = __fadd_rn(zv, __fsub_rn(ev, zv));
}

extern "C" void kernel_launch(void* const* d_in, const int* in_sizes, int n_in,
                              void* d_out, int out_size, void* d_ws, size_t ws_size,
                              hipStream_t stream)
{
    const float* z = (const float*)d_in[0];
    const float* e = (const float*)d_in[1];
    float* out = (float*)d_out;

    char* ws = (char*)d_ws;
    const size_t MB = 1024 * 1024, KB = 1024;
    uint16_t* zb  = (uint16_t*)(ws);                    // 2 MB
    uint16_t* eb  = (uint16_t*)(ws + 2 * MB);           // 1 MB
    float* cmaxb  = (float*)(ws + 3 * MB);              // 4 MB
    float* sz_arr = (float*)(ws + 7 * MB);              // 64 KB
    float* se_arr = (float*)(ws + 7 * MB + 64 * KB);    // 32 KB

    vq_convert  <<<dim3(768),                dim3(256), 0, stream>>>(z, e, (uint32_t*)zb, (uint32_t*)eb);
    vq_prep     <<<dim3((NROWS + NE) / 256), dim3(256), 0, stream>>>(z, e, sz_arr, se_arr);
    vq_scan_mfma<<<dim3(2048),               dim3(256), 0, stream>>>(zb, eb, cmaxb);
    vq_rescore  <<<dim3(NROWS / 4),          dim3(256), 0, stream>>>(z, e, sz_arr, se_arr, cmaxb, out);
    vq_zq       <<<dim3(NROWS * D / 256),    dim3(256), 0, stream>>>(z, e, out);
}

// Round 9
// 156.751 us; speedup vs baseline: 2.9553x; 1.6646x over previous
//
#include <hip/hip_runtime.h>
#include <stdint.h>

// VectorQuantizer — f32 I/O confirmed. d_in[0]=z [16384,64], d_in[1]=e [8192,64];
// d_out f32: [z_q 16384*64][idx-as-float 16384]. d_ws >= 16MB confirmed.
//
// FROZEN exact numerics (rescore path only):
//   sz,se: scalar pairwise-8; c: 4 lanes (k mod 4), mul/add separately rounded,
//   16-chunks ascending, reversed sub-blocks (+12,+8,+4,+0), hadd (q0+q1)+(q2+q3);
//   A=fl(sz+se); d=fl(A-2c); argmin strict-<, first (smallest) index wins.
//
// Round-9: rescore reads a TRANSPOSED f32 copy e_t[64][8192] so the wave's loads
// are coalesced (round-8 disease: row-per-lane 512B-stride loads -> each vmem
// instruction touched 64 cache lines -> TA serialization, VALUBusy 8%).
// Per k (frozen order), lane loads e_t[k][j0+2l] as float2 = 512 B contiguous
// per wave; z[k] via LDS broadcast. Accumulator-order bit-identical.

#define NROWS 16384
#define NE    8192
#define D     64
#define BN    128
#define NCH   (NE / BN)     // 64
#define BAND  1.25e-4f

typedef __attribute__((ext_vector_type(8))) short short8;
typedef __attribute__((ext_vector_type(4))) float f32x4;

// ---------- frozen exact helpers ----------
__device__ __forceinline__ float sumsq_pairwise8(const float* x) {
    float r8[8];
    #pragma unroll
    for (int l = 0; l < 8; ++l) r8[l] = __fmul_rn(x[l], x[l]);
    #pragma unroll
    for (int i = 8; i < 64; i += 8)
        #pragma unroll
        for (int l = 0; l < 8; ++l)
            r8[l] = __fadd_rn(r8[l], __fmul_rn(x[i + l], x[i + l]));
    return __fadd_rn(__fadd_rn(__fadd_rn(r8[0], r8[1]), __fadd_rn(r8[2], r8[3])),
                     __fadd_rn(__fadd_rn(r8[4], r8[5]), __fadd_rn(r8[6], r8[7])));
}

__device__ __forceinline__ uint32_t bf16rn(float f) {
    union { float f; uint32_t u; } c; c.f = f;
    return (c.u + 0x7FFFu + ((c.u >> 16) & 1u)) >> 16;
}
__device__ __forceinline__ uint32_t pk2(float lo, float hi) {
    return bf16rn(lo) | (bf16rn(hi) << 16);
}

// ---------- phase 0a: f32 -> bf16 (RN) ----------
__global__ __launch_bounds__(256)
void vq_convert(const float* __restrict__ z, const float* __restrict__ e,
                uint32_t* __restrict__ zb, uint32_t* __restrict__ eb)
{
    const int i = blockIdx.x * 256 + threadIdx.x;
    const int nz = NROWS * D / 8;
    const int ne = NE * D / 8;
    if (i < nz) {
        const float4 a = ((const float4*)z)[i * 2];
        const float4 b = ((const float4*)z)[i * 2 + 1];
        uint4 o; o.x = pk2(a.x, a.y); o.y = pk2(a.z, a.w);
        o.z = pk2(b.x, b.y); o.w = pk2(b.z, b.w);
        ((uint4*)zb)[i] = o;
    } else if (i < nz + ne) {
        const int k = i - nz;
        const float4 a = ((const float4*)e)[k * 2];
        const float4 b = ((const float4*)e)[k * 2 + 1];
        uint4 o; o.x = pk2(a.x, a.y); o.y = pk2(a.z, a.w);
        o.z = pk2(b.x, b.y); o.w = pk2(b.z, b.w);
        ((uint4*)eb)[k] = o;
    }
}

// ---------- phase 0b: exact sz[row], se[j] ----------
__global__ __launch_bounds__(256)
void vq_prep(const float* __restrict__ z, const float* __restrict__ e,
             float* __restrict__ sz_arr, float* __restrict__ se_arr)
{
    const int i = blockIdx.x * 256 + threadIdx.x;
    const float* p;
    float* dst;
    if (i < NROWS) { p = z + (size_t)i * D; dst = sz_arr + i; }
    else if (i < NROWS + NE) { p = e + (size_t)(i - NROWS) * D; dst = se_arr + (i - NROWS); }
    else return;
    float x[D];
    #pragma unroll
    for (int k = 0; k < D; k += 4) {
        const float4 v = *(const float4*)(p + k);
        x[k] = v.x; x[k + 1] = v.y; x[k + 2] = v.z; x[k + 3] = v.w;
    }
    *dst = sumsq_pairwise8(x);
}

// ---------- phase 0c: e [8192][64] -> e_t [64][8192] (LDS tiled) ----------
__global__ __launch_bounds__(256)
void vq_transpose(const float* __restrict__ e, float* __restrict__ et)
{
    __shared__ float tile[64][65];
    const int t  = threadIdx.x;
    const int j0 = blockIdx.x * 64;
    const int r  = t >> 4;        // 0..15
    const int c4 = t & 15;        // 0..15

    #pragma unroll
    for (int rr = 0; rr < 4; ++rr) {
        const int row = rr * 16 + r;
        const float4 v = *(const float4*)(e + (size_t)(j0 + row) * D + c4 * 4);
        tile[row][c4 * 4 + 0] = v.x; tile[row][c4 * 4 + 1] = v.y;
        tile[row][c4 * 4 + 2] = v.z; tile[row][c4 * 4 + 3] = v.w;
    }
    __syncthreads();
    #pragma unroll
    for (int rr = 0; rr < 4; ++rr) {
        const int k = rr * 16 + r;
        float4 o;
        o.x = tile[c4 * 4 + 0][k]; o.y = tile[c4 * 4 + 1][k];
        o.z = tile[c4 * 4 + 2][k]; o.w = tile[c4 * 4 + 3][k];
        *(float4*)(et + (size_t)k * NE + j0 + c4 * 4) = o;
    }
}

// ---------- phase 1: MFMA GEMM + per-(row,chunk) max (verified, unchanged) ----------
__global__ __launch_bounds__(256)
void vq_scan_mfma(const uint16_t* __restrict__ zb, const uint16_t* __restrict__ eb,
                  float* __restrict__ cmax)
{
    __shared__ uint16_t elds[BN][72];
    __shared__ float    rmld[4][64][20];

    const int tid  = threadIdx.x;
    const int lane = tid & 63, w = tid >> 6;
    const int mb   = blockIdx.x >> 5;
    const int jb   = blockIdx.x & 31;
    const int row0 = mb * 256 + w * 64;
    const int l15  = lane & 15, l4 = lane >> 4;

    short8 af[4][2];
    #pragma unroll
    for (int m = 0; m < 4; ++m)
        #pragma unroll
        for (int h = 0; h < 2; ++h)
            af[m][h] = *(const short8*)(zb + (size_t)(row0 + m * 16 + l15) * D + h * 32 + l4 * 8);

    const f32x4 z4 = {0.f, 0.f, 0.f, 0.f};

    #pragma unroll 1
    for (int c = 0; c < 2; ++c) {
        const int j0 = jb * 256 + c * BN;
        {
            const int srow = tid >> 1, shalf = tid & 1;
            const uint16_t* sp = eb + (size_t)(j0 + srow) * D + shalf * 32;
            uint16_t* dp = &elds[srow][shalf * 32];
            #pragma unroll
            for (int q = 0; q < 4; ++q)
                *(short8*)(dp + q * 8) = *(const short8*)(sp + q * 8);
        }
        __syncthreads();

        f32x4 rm[4];
        #pragma unroll
        for (int m = 0; m < 4; ++m) rm[m] = {-3.0e38f, -3.0e38f, -3.0e38f, -3.0e38f};

        #pragma unroll 1
        for (int n = 0; n < 8; ++n) {
            const uint16_t* bp = &elds[n * 16 + l15][l4 * 8];
            const short8 b0 = *(const short8*)(bp);
            const short8 b1 = *(const short8*)(bp + 32);
            #pragma unroll
            for (int m = 0; m < 4; ++m) {
                f32x4 acc = __builtin_amdgcn_mfma_f32_16x16x32_bf16(af[m][0], b0, z4, 0, 0, 0);
                acc = __builtin_amdgcn_mfma_f32_16x16x32_bf16(af[m][1], b1, acc, 0, 0, 0);
                #pragma unroll
                for (int r = 0; r < 4; ++r) rm[m][r] = fmaxf(rm[m][r], acc[r]);
            }
        }

        #pragma unroll
        for (int m = 0; m < 4; ++m)
            *(f32x4*)&rmld[w][lane][m * 4] = rm[m];
        const int r  = lane;
        const int mm = r >> 4, rg = r & 3, lg = ((r & 15) >> 2) * 16;
        float v = rmld[w][lg][mm * 4 + rg];
        #pragma unroll
        for (int i = 1; i < 16; ++i) v = fmaxf(v, rmld[w][lg + i][mm * 4 + rg]);
        cmax[(size_t)(row0 + r) * NCH + (jb * 2 + c)] = v;
        __syncthreads();
    }
}

// ---------- phase 2: coalesced exact rescore (wave per row, e_t reads) ----------
__global__ __launch_bounds__(256)
void vq_rescore(const float* __restrict__ z, const float* __restrict__ et,
                const float* __restrict__ sz_arr, const float* __restrict__ se_arr,
                const float* __restrict__ cmax, float* __restrict__ out)
{
    __shared__ float zl[4][D];

    const int lane = threadIdx.x & 63, w = threadIdx.x >> 6;
    const int row = blockIdx.x * 4 + w;

    const float ci = cmax[(size_t)row * NCH + lane];
    float cm = ci;
    #pragma unroll
    for (int o = 1; o < 64; o <<= 1) cm = fmaxf(cm, __shfl_xor(cm, o, 64));
    unsigned long long sel = __ballot(ci >= cm - BAND);

    zl[w][lane] = z[(size_t)row * D + lane];   // same-wave DS in-order

    const float sz = sz_arr[row];

    float bd = 3.0e38f; int bj = 0x7FFFFFFF;
    while (sel) {
        const int ch = __builtin_ctzll(sel); sel &= sel - 1;   // ascending chunks
        const int j0 = ch * BN + lane * 2;                      // lane owns j0, j0+1

        // frozen dot order per accumulator: cc ascending, granules +12,+8,+4,+0;
        // q_i accumulates k===i (mod 4); mul and add separately rounded.
        float q00 = 0.f, q01 = 0.f, q02 = 0.f, q03 = 0.f;   // j0
        float q10 = 0.f, q11 = 0.f, q12 = 0.f, q13 = 0.f;   // j0+1
        #pragma unroll
        for (int cc = 0; cc < 4; ++cc) {
            #pragma unroll
            for (int sb = 3; sb >= 0; --sb) {
                const int b = cc * 16 + sb * 4;
                // coalesced: wave reads 512 B contiguous of e_t row k
                const float2 e0 = *(const float2*)(et + (size_t)(b + 0) * NE + j0);
                const float2 e1 = *(const float2*)(et + (size_t)(b + 1) * NE + j0);
                const float2 e2 = *(const float2*)(et + (size_t)(b + 2) * NE + j0);
                const float2 e3 = *(const float2*)(et + (size_t)(b + 3) * NE + j0);
                const float z0 = zl[w][b + 0], z1 = zl[w][b + 1];   // LDS broadcast
                const float z2 = zl[w][b + 2], z3 = zl[w][b + 3];
                q00 = __fadd_rn(q00, __fmul_rn(z0, e0.x));
                q01 = __fadd_rn(q01, __fmul_rn(z1, e1.x));
                q02 = __fadd_rn(q02, __fmul_rn(z2, e2.x));
                q03 = __fadd_rn(q03, __fmul_rn(z3, e3.x));
                q10 = __fadd_rn(q10, __fmul_rn(z0, e0.y));
                q11 = __fadd_rn(q11, __fmul_rn(z1, e1.y));
                q12 = __fadd_rn(q12, __fmul_rn(z2, e2.y));
                q13 = __fadd_rn(q13, __fmul_rn(z3, e3.y));
            }
        }
        const float c0 = __fadd_rn(__fadd_rn(q00, q01), __fadd_rn(q02, q03));
        const float c1 = __fadd_rn(__fadd_rn(q10, q11), __fadd_rn(q12, q13));
        const float A0 = __fadd_rn(sz, se_arr[j0]);
        const float A1 = __fadd_rn(sz, se_arr[j0 + 1]);
        const float d0 = __fsub_rn(A0, __fadd_rn(c0, c0));
        const float d1 = __fsub_rn(A1, __fadd_rn(c1, c1));

        float d = d0; int j = j0;
        if (d1 < d) { d = d1; j = j0 + 1; }                 // tie keeps smaller j
        #pragma unroll
        for (int o = 1; o < 64; o <<= 1) {
            const float od = __shfl_xor(d, o, 64);
            const int   oj = __shfl_xor(j, o, 64);
            if (od < d || (od == d && oj < j)) { d = od; j = oj; }
        }
        if (d < bd || (d == bd && j < bj)) { bd = d; bj = j; }
    }
    if (lane == 0) out[(size_t)NROWS * D + row] = (float)bj;
}

// ---------- phase 3: z_q = fl(z + fl(e[idx] - z)) ----------
__global__ __launch_bounds__(256)
void vq_zq(const float* __restrict__ z, const float* __restrict__ e,
           float* __restrict__ out)
{
    const size_t m = (size_t)blockIdx.x * 256 + threadIdx.x;
    const int r = (int)(m >> 6), k = (int)(m & 63);
    const int sel = (int)out[(size_t)NROWS * D + r];
    const float zv = z[m];
    const float ev = e[(size_t)sel * D + k];
    out[m] = __fadd_rn(zv, __fsub_rn(ev, zv));
}

extern "C" void kernel_launch(void* const* d_in, const int* in_sizes, int n_in,
                              void* d_out, int out_size, void* d_ws, size_t ws_size,
                              hipStream_t stream)
{
    const float* z = (const float*)d_in[0];
    const float* e = (const float*)d_in[1];
    float* out = (float*)d_out;

    char* ws = (char*)d_ws;
    const size_t MB = 1024 * 1024, KB = 1024;
    uint16_t* zb  = (uint16_t*)(ws);                    // 0..2 MB
    uint16_t* eb  = (uint16_t*)(ws + 2 * MB);           // 2..3 MB
    float* cmaxb  = (float*)(ws + 3 * MB);              // 3..7 MB
    float* sz_arr = (float*)(ws + 7 * MB);              // 64 KB
    float* se_arr = (float*)(ws + 7 * MB + 64 * KB);    // 32 KB
    float* e_t    = (float*)(ws + 8 * MB);              // 8..10 MB

    vq_convert  <<<dim3(768),                dim3(256), 0, stream>>>(z, e, (uint32_t*)zb, (uint32_t*)eb);
    vq_prep     <<<dim3((NROWS + NE) / 256), dim3(256), 0, stream>>>(z, e, sz_arr, se_arr);
    vq_transpose<<<dim3(NE / 64),            dim3(256), 0, stream>>>(e, e_t);
    vq_scan_mfma<<<dim3(2048),               dim3(256), 0, stream>>>(zb, eb, cmaxb);
    vq_rescore  <<<dim3(NROWS / 4),          dim3(256), 0, stream>>>(z, e_t, sz_arr, se_arr, cmaxb, out);
    vq_zq       <<<dim3(NROWS * D / 256),    dim3(256), 0, stream>>>(z, e, out);
}